// Round 1
// baseline (459.720 us; speedup 1.0000x reference)
//
#include <hip/hip_runtime.h>

// Problem constants (LEVEL=10)
constexpr int S  = 2048;
constexpr int HS = 1024;
constexpr int B  = 2;
constexpr int F  = 5;
constexpr int PL = HS * S;               // per-(b,f) x plane elements
constexpr int OD = F * PL;               // out stride per direction d
constexpr int WI = (HS - 2) * (S - 2);   // per-k w_inner plane elements

// out layout: (B, 4, F, HS, S): off = b*4*OD + d*OD + f*PL + i*S + j
// x   layout: (B, F, HS, S):    off = (b*F + f)*PL + i*S + j
//
// _wp / _wn in the reference roll along axis=1 of slices whose spatial dim has
// been scalar-indexed -> axis 1 is the FEATURE axis. So _wp reads feature
// (f-1)%F, _wn reads (f+1)%F, position unchanged.

__global__ __launch_bounds__(256)
void icok(const float* __restrict__ x, const float* __restrict__ poles,
          const float* __restrict__ w_inner, const float* __restrict__ w_east,
          const float* __restrict__ w_cn, const float* __restrict__ w_ne,
          const float* __restrict__ w_nne, const float* __restrict__ w_nw,
          const float* __restrict__ w_nww, const float* __restrict__ w_west,
          float* __restrict__ out)
{
    const int gid = blockIdx.x * 256 + threadIdx.x;
    const int i = gid >> 11;        // row (0..HS-1)
    const int j = gid & (S - 1);    // col (0..S-1)

    // ---- zero borders: whole column 0, and row HS-1 cols 1..HS-1 ----
    if (j == 0 || (i == HS - 1 && j < HS)) {
        for (int b = 0; b < B; ++b) {
#pragma unroll
            for (int f = 0; f < F; ++f) {
                float* ob = out + b * (4 * OD) + f * PL + i * S + j;
                ob[0] = 0.f; ob[OD] = 0.f; ob[2 * OD] = 0.f; ob[3 * OD] = 0.f;
            }
        }
        return;
    }

    // ---- interior: 1<=i<=HS-2, 1<=j<=S-2 ----
    if (i > 0 && i < HS - 1 && j < S - 1) {
        const int wo = (i - 1) * (S - 2) + (j - 1);
        const float w0 = w_inner[wo];
        const float w1 = w_inner[wo + WI];
        const float w2 = w_inner[wo + 2 * WI];
        const float w3 = w_inner[wo + 3 * WI];
        const float w4 = w_inner[wo + 4 * WI];
        const float w5 = w_inner[wo + 5 * WI];
        const int rm = (i - 1) * S + j;
        const int rc = i * S + j;
        const int rp = (i + 1) * S + j;
        for (int b = 0; b < B; ++b) {
#pragma unroll
            for (int f = 0; f < F; ++f) {
                const float* xb = x + (b * F + f) * PL;
                const float xi = xb[rc];
                const float d0 = (xb[rm - 1] - xi) * w0;
                const float d1 = (xb[rp + 1] - xi) * w1;
                const float d2 = (xb[rm] - xi) * w2 + (xb[rc + 1] - xi) * w3;
                const float d3 = (xb[rc - 1] - xi) * w4 + (xb[rp] - xi) * w5;
                float* ob = out + b * (4 * OD) + f * PL + rc;
                ob[0] = d0; ob[OD] = d1; ob[2 * OD] = d2; ob[3 * OD] = d3;
            }
        }
        return;
    }

    if (i == 0) {
        if (j < HS) {
            // ---- EAST: i=0, j in 1..HS-1, t=j-1, w_east[k][t], k-stride HS-1
            const int t = j - 1;
            const float w0 = w_east[t];
            const float w1 = w_east[t + (HS - 1)];
            const float w2 = w_east[t + 2 * (HS - 1)];
            const float w3 = w_east[t + 3 * (HS - 1)];
            const float w4 = w_east[t + 4 * (HS - 1)];
            const float w5 = w_east[t + 5 * (HS - 1)];
            for (int b = 0; b < B; ++b) {
#pragma unroll
                for (int f = 0; f < F; ++f) {
                    const int fm = (f == 0) ? F - 1 : f - 1;
                    const float* xb  = x + (b * F + f) * PL;
                    const float* xmb = x + (b * F + fm) * PL;
                    const float xi = xb[j];
                    const float d0 = (xmb[(HS - 1) * S + HS + t] - xi) * w0;
                    const float d1 = (xb[S + 2 + t] - xi) * w1;
                    const float d2 = (xmb[(HS - 1) * S + HS + 1 + t] - xi) * w2
                                   + (xb[2 + t] - xi) * w3;
                    const float d3 = (xb[t] - xi) * w4 + (xb[S + 1 + t] - xi) * w5;
                    float* ob = out + b * (4 * OD) + f * PL + j;
                    ob[0] = d0; ob[OD] = d1; ob[2 * OD] = d2; ob[3 * OD] = d3;
                }
            }
        } else if (j == HS) {
            // ---- CN: i=0, j=HS ----
            const float w0 = w_cn[0], w1 = w_cn[1], w2 = w_cn[2], w3 = w_cn[3], w4 = w_cn[4];
            for (int b = 0; b < B; ++b) {
#pragma unroll
                for (int f = 0; f < F; ++f) {
                    const int fm = (f == 0) ? F - 1 : f - 1;
                    const float* xb  = x + (b * F + f) * PL;
                    const float* xmb = x + (b * F + fm) * PL;
                    const float xi = xb[HS];
                    const float d0 = (xmb[(HS - 1) * S + S - 1] - xi) * w0;
                    const float d1 = (xb[S + HS + 1] - xi) * w1;
                    const float d2 = (xb[HS + 1] - xi) * w2;
                    const float d3 = (xb[HS - 1] - xi) * w3 + (xb[S + HS] - xi) * w4;
                    float* ob = out + b * (4 * OD) + f * PL + HS;
                    ob[0] = d0; ob[OD] = d1; ob[2 * OD] = d2; ob[3 * OD] = d3;
                }
            }
        } else if (j < S - 1) {
            // ---- NE: i=0, j in HS+1..S-2, t=j-HS-1, w_ne[k][t], k-stride HS-2
            const int t = j - HS - 1;
            const float w0 = w_ne[t];
            const float w1 = w_ne[t + (HS - 2)];
            const float w2 = w_ne[t + 2 * (HS - 2)];
            const float w3 = w_ne[t + 3 * (HS - 2)];
            const float w4 = w_ne[t + 4 * (HS - 2)];
            const float w5 = w_ne[t + 5 * (HS - 2)];
            for (int b = 0; b < B; ++b) {
#pragma unroll
                for (int f = 0; f < F; ++f) {
                    const int fm = (f == 0) ? F - 1 : f - 1;
                    const float* xb  = x + (b * F + f) * PL;
                    const float* xmb = x + (b * F + fm) * PL;
                    const float xi = xb[j];
                    const float d0 = (xmb[(HS - 2 - t) * S + S - 1] - xi) * w0
                                   + (xmb[(HS - 1 - t) * S + S - 1] - xi) * w1;
                    const float d1 = (xb[S + HS + 2 + t] - xi) * w2
                                   + (xb[S + HS + 1 + t] - xi) * w3;
                    const float d2 = (xb[HS + 2 + t] - xi) * w4;
                    const float d3 = (xb[HS + t] - xi) * w5;
                    float* ob = out + b * (4 * OD) + f * PL + j;
                    ob[0] = d0; ob[OD] = d1; ob[2 * OD] = d2; ob[3 * OD] = d3;
                }
            }
        } else {
            // ---- NNE: i=0, j=S-1 ----
            const float w0 = w_nne[0], w1 = w_nne[1], w2 = w_nne[2],
                        w3 = w_nne[3], w4 = w_nne[4], w5 = w_nne[5];
            for (int b = 0; b < B; ++b) {
#pragma unroll
                for (int f = 0; f < F; ++f) {
                    const int fm = (f == 0) ? F - 1 : f - 1;
                    const int fp = (f == F - 1) ? 0 : f + 1;
                    const float* xb  = x + (b * F + f) * PL;
                    const float* xmb = x + (b * F + fm) * PL;
                    const float* xpb = x + (b * F + fp) * PL;
                    const float xi = xb[S - 1];
                    const float d0 = (xmb[S - 1] - xi) * w0 + (xmb[S + S - 1] - xi) * w1;
                    const float d1 = (xpb[S - 1] - xi) * w2 + (xb[S + S - 1] - xi) * w3;
                    const float d2 = (poles[b * 2 + 1] - xi) * w4;
                    const float d3 = (xb[S - 2] - xi) * w5;
                    float* ob = out + b * (4 * OD) + f * PL + (S - 1);
                    ob[0] = d0; ob[OD] = d1; ob[2 * OD] = d2; ob[3 * OD] = d3;
                }
            }
        }
        return;
    }

    if (i == HS - 1) {
        if (j < S - 1) {
            // ---- WEST: i=HS-1, j in HS..S-2, t=j-HS, w_west[k][t], k-stride HS-1
            const int t = j - HS;
            const float w0 = w_west[t];
            const float w1 = w_west[t + (HS - 1)];
            const float w2 = w_west[t + 2 * (HS - 1)];
            const float w3 = w_west[t + 3 * (HS - 1)];
            const float w4 = w_west[t + 4 * (HS - 1)];
            const float w5 = w_west[t + 5 * (HS - 1)];
            for (int b = 0; b < B; ++b) {
#pragma unroll
                for (int f = 0; f < F; ++f) {
                    const int fp = (f == F - 1) ? 0 : f + 1;
                    const float* xb  = x + (b * F + f) * PL;
                    const float* xpb = x + (b * F + fp) * PL;
                    const float xi = xb[(HS - 1) * S + j];
                    const float d0 = (xb[(HS - 2) * S + HS - 1 + t] - xi) * w0;
                    const float d1 = (xpb[1 + t] - xi) * w1;
                    const float d2 = (xb[(HS - 2) * S + HS + t] - xi) * w2
                                   + (xb[(HS - 1) * S + HS + 1 + t] - xi) * w3;
                    const float d3 = (xb[(HS - 1) * S + HS - 1 + t] - xi) * w4
                                   + (xpb[t] - xi) * w5;
                    float* ob = out + b * (4 * OD) + f * PL + (HS - 1) * S + j;
                    ob[0] = d0; ob[OD] = d1; ob[2 * OD] = d2; ob[3 * OD] = d3;
                }
            }
        } else {
            // ---- NWW: i=HS-1, j=S-1 ----
            const float w0 = w_nww[0], w1 = w_nww[1], w2 = w_nww[2],
                        w3 = w_nww[3], w4 = w_nww[4], w5 = w_nww[5];
            for (int b = 0; b < B; ++b) {
#pragma unroll
                for (int f = 0; f < F; ++f) {
                    const int fp = (f == F - 1) ? 0 : f + 1;
                    const float* xb  = x + (b * F + f) * PL;
                    const float* xpb = x + (b * F + fp) * PL;
                    const float xi = xb[(HS - 1) * S + S - 1];
                    const float d0 = (xb[(HS - 2) * S + S - 2] - xi) * w0;
                    const float d1 = (xpb[HS] - xi) * w1;
                    const float d2 = (xb[(HS - 2) * S + S - 1] - xi) * w2
                                   + (xpb[HS + 1] - xi) * w3;
                    const float d3 = (xb[(HS - 1) * S + S - 2] - xi) * w4
                                   + (xpb[HS - 1] - xi) * w5;
                    float* ob = out + b * (4 * OD) + f * PL + (HS - 1) * S + (S - 1);
                    ob[0] = d0; ob[OD] = d1; ob[2 * OD] = d2; ob[3 * OD] = d3;
                }
            }
        }
        return;
    }

    // ---- NW: i in 1..HS-2, j=S-1, t=i-1, w_nw[k][t], k-stride HS-2 ----
    {
        const int t = i - 1;
        const float w0 = w_nw[t];
        const float w1 = w_nw[t + (HS - 2)];
        const float w2 = w_nw[t + 2 * (HS - 2)];
        const float w3 = w_nw[t + 3 * (HS - 2)];
        const float w4 = w_nw[t + 4 * (HS - 2)];
        const float w5 = w_nw[t + 5 * (HS - 2)];
        for (int b = 0; b < B; ++b) {
#pragma unroll
            for (int f = 0; f < F; ++f) {
                const int fp = (f == F - 1) ? 0 : f + 1;
                const float* xb  = x + (b * F + f) * PL;
                const float* xpb = x + (b * F + fp) * PL;
                const float xi = xb[i * S + S - 1];
                const float d0 = (xb[(i - 1) * S + S - 2] - xi) * w0;
                const float d1 = (xpb[S - 2 - t] - xi) * w1;
                const float d2 = (xb[(i - 1) * S + S - 1] - xi) * w2
                               + (xpb[S - 1 - t] - xi) * w3;
                const float d3 = (xb[i * S + S - 2] - xi) * w4
                               + (xb[(i + 1) * S + S - 1] - xi) * w5;
                float* ob = out + b * (4 * OD) + f * PL + i * S + (S - 1);
                ob[0] = d0; ob[OD] = d1; ob[2 * OD] = d2; ob[3 * OD] = d3;
            }
        }
    }
}

extern "C" void kernel_launch(void* const* d_in, const int* in_sizes, int n_in,
                              void* d_out, int out_size, void* d_ws, size_t ws_size,
                              hipStream_t stream) {
    const float* x       = (const float*)d_in[0];
    const float* poles   = (const float*)d_in[1];
    const float* w_inner = (const float*)d_in[2];
    const float* w_east  = (const float*)d_in[3];
    const float* w_cn    = (const float*)d_in[4];
    const float* w_ne    = (const float*)d_in[5];
    const float* w_nne   = (const float*)d_in[6];
    const float* w_nw    = (const float*)d_in[7];
    const float* w_nww   = (const float*)d_in[8];
    const float* w_west  = (const float*)d_in[9];
    float* out = (float*)d_out;

    const int total = HS * S;               // 2,097,152
    dim3 grid(total / 256), block(256);
    hipLaunchKernelGGL(icok, grid, block, 0, stream,
                       x, poles, w_inner, w_east, w_cn, w_ne, w_nne, w_nw,
                       w_nww, w_west, out);
}

// Round 2
// 458.239 us; speedup vs baseline: 1.0032x; 1.0032x over previous
//
#include <hip/hip_runtime.h>

// Problem constants (LEVEL=10)
constexpr int S  = 2048;
constexpr int HS = 1024;
constexpr int B  = 2;
constexpr int F  = 5;
constexpr int PL = HS * S;               // per-(b,f) x plane elements
constexpr int OD = F * PL;               // out stride per direction d
constexpr int WI = (HS - 2) * (S - 2);   // per-k w_inner plane elements

typedef float v4  __attribute__((ext_vector_type(4)));
typedef float v4u __attribute__((ext_vector_type(4), aligned(4)));

__device__ __forceinline__ void st_nt(float* p, v4 v) {
    __builtin_nontemporal_store(v, (v4*)p);
}

// ---------- scalar path: handles ANY (i,j) — verified in round 0 ----------
__device__ void scalar_point(
    int i, int j,
    const float* __restrict__ x, const float* __restrict__ poles,
    const float* __restrict__ w_inner, const float* __restrict__ w_east,
    const float* __restrict__ w_cn, const float* __restrict__ w_ne,
    const float* __restrict__ w_nne, const float* __restrict__ w_nw,
    const float* __restrict__ w_nww, const float* __restrict__ w_west,
    float* __restrict__ out)
{
    // zero borders: whole column 0, and row HS-1 cols 1..HS-1
    if (j == 0 || (i == HS - 1 && j < HS)) {
        for (int b = 0; b < B; ++b) {
#pragma unroll
            for (int f = 0; f < F; ++f) {
                float* ob = out + b * (4 * OD) + f * PL + i * S + j;
                ob[0] = 0.f; ob[OD] = 0.f; ob[2 * OD] = 0.f; ob[3 * OD] = 0.f;
            }
        }
        return;
    }

    // interior
    if (i > 0 && i < HS - 1 && j < S - 1) {
        const int wo = (i - 1) * (S - 2) + (j - 1);
        const float w0 = w_inner[wo];
        const float w1 = w_inner[wo + WI];
        const float w2 = w_inner[wo + 2 * WI];
        const float w3 = w_inner[wo + 3 * WI];
        const float w4 = w_inner[wo + 4 * WI];
        const float w5 = w_inner[wo + 5 * WI];
        const int rm = (i - 1) * S + j;
        const int rc = i * S + j;
        const int rp = (i + 1) * S + j;
        for (int b = 0; b < B; ++b) {
#pragma unroll
            for (int f = 0; f < F; ++f) {
                const float* xb = x + (b * F + f) * PL;
                const float xi = xb[rc];
                const float d0 = (xb[rm - 1] - xi) * w0;
                const float d1 = (xb[rp + 1] - xi) * w1;
                const float d2 = (xb[rm] - xi) * w2 + (xb[rc + 1] - xi) * w3;
                const float d3 = (xb[rc - 1] - xi) * w4 + (xb[rp] - xi) * w5;
                float* ob = out + b * (4 * OD) + f * PL + rc;
                ob[0] = d0; ob[OD] = d1; ob[2 * OD] = d2; ob[3 * OD] = d3;
            }
        }
        return;
    }

    if (i == 0) {
        if (j < HS) {
            // EAST: i=0, j in 1..HS-1
            const int t = j - 1;
            const float w0 = w_east[t];
            const float w1 = w_east[t + (HS - 1)];
            const float w2 = w_east[t + 2 * (HS - 1)];
            const float w3 = w_east[t + 3 * (HS - 1)];
            const float w4 = w_east[t + 4 * (HS - 1)];
            const float w5 = w_east[t + 5 * (HS - 1)];
            for (int b = 0; b < B; ++b) {
#pragma unroll
                for (int f = 0; f < F; ++f) {
                    const int fm = (f == 0) ? F - 1 : f - 1;
                    const float* xb  = x + (b * F + f) * PL;
                    const float* xmb = x + (b * F + fm) * PL;
                    const float xi = xb[j];
                    const float d0 = (xmb[(HS - 1) * S + HS + t] - xi) * w0;
                    const float d1 = (xb[S + 2 + t] - xi) * w1;
                    const float d2 = (xmb[(HS - 1) * S + HS + 1 + t] - xi) * w2
                                   + (xb[2 + t] - xi) * w3;
                    const float d3 = (xb[t] - xi) * w4 + (xb[S + 1 + t] - xi) * w5;
                    float* ob = out + b * (4 * OD) + f * PL + j;
                    ob[0] = d0; ob[OD] = d1; ob[2 * OD] = d2; ob[3 * OD] = d3;
                }
            }
        } else if (j == HS) {
            // CN
            const float w0 = w_cn[0], w1 = w_cn[1], w2 = w_cn[2], w3 = w_cn[3], w4 = w_cn[4];
            for (int b = 0; b < B; ++b) {
#pragma unroll
                for (int f = 0; f < F; ++f) {
                    const int fm = (f == 0) ? F - 1 : f - 1;
                    const float* xb  = x + (b * F + f) * PL;
                    const float* xmb = x + (b * F + fm) * PL;
                    const float xi = xb[HS];
                    const float d0 = (xmb[(HS - 1) * S + S - 1] - xi) * w0;
                    const float d1 = (xb[S + HS + 1] - xi) * w1;
                    const float d2 = (xb[HS + 1] - xi) * w2;
                    const float d3 = (xb[HS - 1] - xi) * w3 + (xb[S + HS] - xi) * w4;
                    float* ob = out + b * (4 * OD) + f * PL + HS;
                    ob[0] = d0; ob[OD] = d1; ob[2 * OD] = d2; ob[3 * OD] = d3;
                }
            }
        } else if (j < S - 1) {
            // NE: i=0, j in HS+1..S-2
            const int t = j - HS - 1;
            const float w0 = w_ne[t];
            const float w1 = w_ne[t + (HS - 2)];
            const float w2 = w_ne[t + 2 * (HS - 2)];
            const float w3 = w_ne[t + 3 * (HS - 2)];
            const float w4 = w_ne[t + 4 * (HS - 2)];
            const float w5 = w_ne[t + 5 * (HS - 2)];
            for (int b = 0; b < B; ++b) {
#pragma unroll
                for (int f = 0; f < F; ++f) {
                    const int fm = (f == 0) ? F - 1 : f - 1;
                    const float* xb  = x + (b * F + f) * PL;
                    const float* xmb = x + (b * F + fm) * PL;
                    const float xi = xb[j];
                    const float d0 = (xmb[(HS - 2 - t) * S + S - 1] - xi) * w0
                                   + (xmb[(HS - 1 - t) * S + S - 1] - xi) * w1;
                    const float d1 = (xb[S + HS + 2 + t] - xi) * w2
                                   + (xb[S + HS + 1 + t] - xi) * w3;
                    const float d2 = (xb[HS + 2 + t] - xi) * w4;
                    const float d3 = (xb[HS + t] - xi) * w5;
                    float* ob = out + b * (4 * OD) + f * PL + j;
                    ob[0] = d0; ob[OD] = d1; ob[2 * OD] = d2; ob[3 * OD] = d3;
                }
            }
        } else {
            // NNE: i=0, j=S-1
            const float w0 = w_nne[0], w1 = w_nne[1], w2 = w_nne[2],
                        w3 = w_nne[3], w4 = w_nne[4], w5 = w_nne[5];
            for (int b = 0; b < B; ++b) {
#pragma unroll
                for (int f = 0; f < F; ++f) {
                    const int fm = (f == 0) ? F - 1 : f - 1;
                    const int fp = (f == F - 1) ? 0 : f + 1;
                    const float* xb  = x + (b * F + f) * PL;
                    const float* xmb = x + (b * F + fm) * PL;
                    const float* xpb = x + (b * F + fp) * PL;
                    const float xi = xb[S - 1];
                    const float d0 = (xmb[S - 1] - xi) * w0 + (xmb[S + S - 1] - xi) * w1;
                    const float d1 = (xpb[S - 1] - xi) * w2 + (xb[S + S - 1] - xi) * w3;
                    const float d2 = (poles[b * 2 + 1] - xi) * w4;
                    const float d3 = (xb[S - 2] - xi) * w5;
                    float* ob = out + b * (4 * OD) + f * PL + (S - 1);
                    ob[0] = d0; ob[OD] = d1; ob[2 * OD] = d2; ob[3 * OD] = d3;
                }
            }
        }
        return;
    }

    if (i == HS - 1) {
        if (j < S - 1) {
            // WEST: i=HS-1, j in HS..S-2
            const int t = j - HS;
            const float w0 = w_west[t];
            const float w1 = w_west[t + (HS - 1)];
            const float w2 = w_west[t + 2 * (HS - 1)];
            const float w3 = w_west[t + 3 * (HS - 1)];
            const float w4 = w_west[t + 4 * (HS - 1)];
            const float w5 = w_west[t + 5 * (HS - 1)];
            for (int b = 0; b < B; ++b) {
#pragma unroll
                for (int f = 0; f < F; ++f) {
                    const int fp = (f == F - 1) ? 0 : f + 1;
                    const float* xb  = x + (b * F + f) * PL;
                    const float* xpb = x + (b * F + fp) * PL;
                    const float xi = xb[(HS - 1) * S + j];
                    const float d0 = (xb[(HS - 2) * S + HS - 1 + t] - xi) * w0;
                    const float d1 = (xpb[1 + t] - xi) * w1;
                    const float d2 = (xb[(HS - 2) * S + HS + t] - xi) * w2
                                   + (xb[(HS - 1) * S + HS + 1 + t] - xi) * w3;
                    const float d3 = (xb[(HS - 1) * S + HS - 1 + t] - xi) * w4
                                   + (xpb[t] - xi) * w5;
                    float* ob = out + b * (4 * OD) + f * PL + (HS - 1) * S + j;
                    ob[0] = d0; ob[OD] = d1; ob[2 * OD] = d2; ob[3 * OD] = d3;
                }
            }
        } else {
            // NWW: i=HS-1, j=S-1
            const float w0 = w_nww[0], w1 = w_nww[1], w2 = w_nww[2],
                        w3 = w_nww[3], w4 = w_nww[4], w5 = w_nww[5];
            for (int b = 0; b < B; ++b) {
#pragma unroll
                for (int f = 0; f < F; ++f) {
                    const int fp = (f == F - 1) ? 0 : f + 1;
                    const float* xb  = x + (b * F + f) * PL;
                    const float* xpb = x + (b * F + fp) * PL;
                    const float xi = xb[(HS - 1) * S + S - 1];
                    const float d0 = (xb[(HS - 2) * S + S - 2] - xi) * w0;
                    const float d1 = (xpb[HS] - xi) * w1;
                    const float d2 = (xb[(HS - 2) * S + S - 1] - xi) * w2
                                   + (xpb[HS + 1] - xi) * w3;
                    const float d3 = (xb[(HS - 1) * S + S - 2] - xi) * w4
                                   + (xpb[HS - 1] - xi) * w5;
                    float* ob = out + b * (4 * OD) + f * PL + (HS - 1) * S + (S - 1);
                    ob[0] = d0; ob[OD] = d1; ob[2 * OD] = d2; ob[3 * OD] = d3;
                }
            }
        }
        return;
    }

    // NW: i in 1..HS-2, j=S-1
    {
        const int t = i - 1;
        const float w0 = w_nw[t];
        const float w1 = w_nw[t + (HS - 2)];
        const float w2 = w_nw[t + 2 * (HS - 2)];
        const float w3 = w_nw[t + 3 * (HS - 2)];
        const float w4 = w_nw[t + 4 * (HS - 2)];
        const float w5 = w_nw[t + 5 * (HS - 2)];
        for (int b = 0; b < B; ++b) {
#pragma unroll
            for (int f = 0; f < F; ++f) {
                const int fp = (f == F - 1) ? 0 : f + 1;
                const float* xb  = x + (b * F + f) * PL;
                const float* xpb = x + (b * F + fp) * PL;
                const float xi = xb[i * S + S - 1];
                const float d0 = (xb[(i - 1) * S + S - 2] - xi) * w0;
                const float d1 = (xpb[S - 2 - t] - xi) * w1;
                const float d2 = (xb[(i - 1) * S + S - 1] - xi) * w2
                               + (xpb[S - 1 - t] - xi) * w3;
                const float d3 = (xb[i * S + S - 2] - xi) * w4
                               + (xb[(i + 1) * S + S - 1] - xi) * w5;
                float* ob = out + b * (4 * OD) + f * PL + i * S + (S - 1);
                ob[0] = d0; ob[OD] = d1; ob[2 * OD] = d2; ob[3 * OD] = d3;
            }
        }
    }
}

// ---------- main kernel ----------
// Blocks 0..2047: vector interior. XCD band swizzle: logical block
// l = (p&7)*256 + (p>>3) so XCD k owns rows 128k+1 .. 128k+128 (vertical halo
// reuse stays in that XCD's 4 MB L2). 2 blocks per row (512 threads x 4 j's).
// Blocks 2048..2095: scalar edge work (rows 0 & HS-1, cols 0..3 & 2044..2047).
__global__ __launch_bounds__(256)
void icok(const float* __restrict__ x, const float* __restrict__ poles,
          const float* __restrict__ w_inner, const float* __restrict__ w_east,
          const float* __restrict__ w_cn, const float* __restrict__ w_ne,
          const float* __restrict__ w_nne, const float* __restrict__ w_nw,
          const float* __restrict__ w_nww, const float* __restrict__ w_west,
          float* __restrict__ out)
{
    const int p = blockIdx.x;

    if (p < 2048) {
        const int l = ((p & 7) << 8) | (p >> 3);
        const int i = 1 + (l >> 1);            // row 1..1024
        if (i > HS - 2) return;                // rows 1023,1024 invalid
        const int jt = ((l & 1) << 8) | threadIdx.x;   // 0..511
        if (jt == 0 || jt == 511) return;      // edge cols handled by edge blocks
        const int j0 = jt << 2;                // 4..2040

        const int wo = (i - 1) * (S - 2) + (j0 - 1);
        const v4 w0v = *(const v4u*)(w_inner + wo);
        const v4 w1v = *(const v4u*)(w_inner + wo + WI);
        const v4 w2v = *(const v4u*)(w_inner + wo + 2 * WI);
        const v4 w3v = *(const v4u*)(w_inner + wo + 3 * WI);
        const v4 w4v = *(const v4u*)(w_inner + wo + 4 * WI);
        const v4 w5v = *(const v4u*)(w_inner + wo + 5 * WI);

        const int rm = (i - 1) * S + j0;
        const int rc = i * S + j0;
        const int rp = (i + 1) * S + j0;

        for (int b = 0; b < B; ++b) {
#pragma unroll
            for (int f = 0; f < F; ++f) {
                const float* xb = x + (b * F + f) * PL;
                const v4 c = *(const v4*)(xb + rc);
                const v4 m = *(const v4*)(xb + rm);
                const v4 pv = *(const v4*)(xb + rp);
                const float ml = xb[rm - 1];
                const float cl = xb[rc - 1];
                const float cr = xb[rc + 4];
                const float pr = xb[rp + 4];
                const v4 xmm1 = {ml, m.x, m.y, m.z};      // x[i-1][j-1..j+2]
                const v4 xpp1 = {pv.y, pv.z, pv.w, pr};   // x[i+1][j+1..j+4]
                const v4 xcm1 = {cl, c.x, c.y, c.z};      // x[i][j-1..j+2]
                const v4 xcp1 = {c.y, c.z, c.w, cr};      // x[i][j+1..j+4]

                const v4 d0 = (xmm1 - c) * w0v;
                const v4 d1 = (xpp1 - c) * w1v;
                const v4 d2 = (m - c) * w2v + (xcp1 - c) * w3v;
                const v4 d3 = (xcm1 - c) * w4v + (pv - c) * w5v;

                float* ob = out + b * (4 * OD) + f * PL + rc;
                st_nt(ob, d0);
                st_nt(ob + OD, d1);
                st_nt(ob + 2 * OD, d2);
                st_nt(ob + 3 * OD, d3);
            }
        }
        return;
    }

    // edge blocks
    const int e = (p - 2048) * 256 + threadIdx.x;
    int i, j;
    if (e < 2048)      { i = 0;      j = e; }
    else if (e < 4096) { i = HS - 1; j = e - 2048; }
    else if (e < 4096 + 8 * (HS - 2)) {
        const int t = e - 4096;
        i = 1 + (t >> 3);
        const int c = t & 7;
        j = (c < 4) ? c : (2040 + c);
    } else return;
    scalar_point(i, j, x, poles, w_inner, w_east, w_cn, w_ne, w_nne,
                 w_nw, w_nww, w_west, out);
}

extern "C" void kernel_launch(void* const* d_in, const int* in_sizes, int n_in,
                              void* d_out, int out_size, void* d_ws, size_t ws_size,
                              hipStream_t stream) {
    const float* x       = (const float*)d_in[0];
    const float* poles   = (const float*)d_in[1];
    const float* w_inner = (const float*)d_in[2];
    const float* w_east  = (const float*)d_in[3];
    const float* w_cn    = (const float*)d_in[4];
    const float* w_ne    = (const float*)d_in[5];
    const float* w_nne   = (const float*)d_in[6];
    const float* w_nw    = (const float*)d_in[7];
    const float* w_nww   = (const float*)d_in[8];
    const float* w_west  = (const float*)d_in[9];
    float* out = (float*)d_out;

    dim3 grid(2048 + 48), block(256);
    hipLaunchKernelGGL(icok, grid, block, 0, stream,
                       x, poles, w_inner, w_east, w_cn, w_ne, w_nne, w_nw,
                       w_nww, w_west, out);
}